// Round 6
// baseline (197.450 us; speedup 1.0000x reference)
//
#include <hip/hip_runtime.h>

#define BB 8
#define SS 4096
#define DD 768
#define NN 64
#define D4 (DD / 4)      // 192 float4 columns
#define TT 64            // tokens per tile (aligned, = SS/NTILES)
#define TPW 16           // tokens per wave (TT / 4 waves)
#define NTILES (SS / TT) // 64 tiles per batch
#define WS_N (BB * NN * DD)  // floats per ws array (393216)

// ---------------- Phase A: zero ws (sums + cnts, 2*WS_N floats) -------------
__global__ __launch_bounds__(256) void zero_ws(float4* ws4) {
    int i = blockIdx.x * 256 + threadIdx.x;   // grid sized exactly 2*WS_N/4/256
    ws4[i] = make_float4(0.f, 0.f, 0.f, 0.f);
}

// ---------------- Phase B: balanced contiguous partial sums ----------------
// grid: BB*NTILES = 512 blocks, 256 threads (4 waves).
// Block = one 64-token tile; wave w streams tokens [t0, t0+16) reading the
// FULL 3 KB row contiguously (3 coalesced 1 KB loads: cols lane, 64+lane,
// 128+lane). Segment boundaries (from LDS ends[]) trigger atomicAdd flushes.
__global__ __launch_bounds__(256) void partial_kernel(
    const float* __restrict__ wv,
    const int* __restrict__ lens,
    float* __restrict__ ws_sum,
    float* __restrict__ ws_cnt)
{
    __shared__ int s_ends[NN];
    const int b    = blockIdx.x >> 6;
    const int tile = blockIdx.x & (NTILES - 1);
    const int tid  = threadIdx.x;
    const int lane = tid & 63;
    const int w    = tid >> 6;

    if (tid < NN) {                       // wave 0: inclusive scan of lens
        int l = lens[b * NN + tid];
        #pragma unroll
        for (int off = 1; off < 64; off <<= 1) {
            int v = __shfl_up(l, off);
            if (lane >= off) l += v;
        }
        s_ends[tid] = l;
    }
    __syncthreads();

    const int t0 = tile * TT + w * TPW;
    // first segment whose end > t0
    int lo = 0, hi = NN - 1;
    while (lo < hi) { int mid = (lo + hi) >> 1; if (s_ends[mid] > t0) hi = mid; else lo = mid + 1; }
    int seg    = lo;
    int segend = s_ends[seg];

    const float4* row = (const float4*)wv + (size_t)(b * SS + t0) * D4;
    float4 s0 = make_float4(0,0,0,0), s1 = s0, s2 = s0;
    float4 c0 = s0, c1 = s0, c2 = s0;

    auto flush = [&](int sg) {
        float* ps = ws_sum + (size_t)(b * NN + sg) * DD;
        float* pc = ws_cnt + (size_t)(b * NN + sg) * DD;
        const int c = lane * 4;
        atomicAdd(ps + c + 0, s0.x); atomicAdd(ps + c + 1, s0.y);
        atomicAdd(ps + c + 2, s0.z); atomicAdd(ps + c + 3, s0.w);
        atomicAdd(ps + 256 + c + 0, s1.x); atomicAdd(ps + 256 + c + 1, s1.y);
        atomicAdd(ps + 256 + c + 2, s1.z); atomicAdd(ps + 256 + c + 3, s1.w);
        atomicAdd(ps + 512 + c + 0, s2.x); atomicAdd(ps + 512 + c + 1, s2.y);
        atomicAdd(ps + 512 + c + 2, s2.z); atomicAdd(ps + 512 + c + 3, s2.w);
        atomicAdd(pc + c + 0, c0.x); atomicAdd(pc + c + 1, c0.y);
        atomicAdd(pc + c + 2, c0.z); atomicAdd(pc + c + 3, c0.w);
        atomicAdd(pc + 256 + c + 0, c1.x); atomicAdd(pc + 256 + c + 1, c1.y);
        atomicAdd(pc + 256 + c + 2, c1.z); atomicAdd(pc + 256 + c + 3, c1.w);
        atomicAdd(pc + 512 + c + 0, c2.x); atomicAdd(pc + 512 + c + 1, c2.y);
        atomicAdd(pc + 512 + c + 2, c2.z); atomicAdd(pc + 512 + c + 3, c2.w);
    };

    #pragma unroll 4
    for (int tok = 0; tok < TPW; ++tok) {
        const int t = t0 + tok;
        if (t >= segend) {                // wave-uniform branch
            flush(seg);
            s0 = s1 = s2 = c0 = c1 = c2 = make_float4(0,0,0,0);
            do { ++seg; segend = s_ends[seg]; } while (t >= segend);
        }
        float4 v0 = row[lane];
        float4 v1 = row[64 + lane];
        float4 v2 = row[128 + lane];
        row += D4;
        s0.x += v0.x; s0.y += v0.y; s0.z += v0.z; s0.w += v0.w;
        s1.x += v1.x; s1.y += v1.y; s1.z += v1.z; s1.w += v1.w;
        s2.x += v2.x; s2.y += v2.y; s2.z += v2.z; s2.w += v2.w;
        c0.x += (v0.x != 0.f) ? 1.f : 0.f; c0.y += (v0.y != 0.f) ? 1.f : 0.f;
        c0.z += (v0.z != 0.f) ? 1.f : 0.f; c0.w += (v0.w != 0.f) ? 1.f : 0.f;
        c1.x += (v1.x != 0.f) ? 1.f : 0.f; c1.y += (v1.y != 0.f) ? 1.f : 0.f;
        c1.z += (v1.z != 0.f) ? 1.f : 0.f; c1.w += (v1.w != 0.f) ? 1.f : 0.f;
        c2.x += (v2.x != 0.f) ? 1.f : 0.f; c2.y += (v2.y != 0.f) ? 1.f : 0.f;
        c2.z += (v2.z != 0.f) ? 1.f : 0.f; c2.w += (v2.w != 0.f) ? 1.f : 0.f;
    }
    flush(seg);
}

// ---------------- Phase C: finalize (mean, fallback, rep, masks) -----------
// grid: BB*NN = 512 blocks, 256 threads (192 active cols).
__global__ __launch_bounds__(256) void finalize_kernel(
    const float* __restrict__ wv,
    const int* __restrict__ rep_ids,
    const float* __restrict__ rep_mask,
    const float* __restrict__ len_mask,
    const float* __restrict__ ws_sum,
    const float* __restrict__ ws_cnt,
    float* __restrict__ out)
{
    __shared__ float s_part[4];
    const int sgid = blockIdx.x;          // b*NN + n
    const int b = sgid >> 6, n = sgid & 63;
    const int tid = threadIdx.x;
    const bool active = tid < D4;

    const float4* sum4 = (const float4*)ws_sum + (size_t)sgid * D4;
    const float4* cnt4 = (const float4*)ws_cnt + (size_t)sgid * D4;
    float4 S = make_float4(0,0,0,0), C = S;
    if (active) { S = sum4[tid]; C = cnt4[tid]; }

    float tot = C.x + C.y + C.z + C.w;    // 0 for inactive lanes
    #pragma unroll
    for (int off = 32; off; off >>= 1) tot += __shfl_xor(tot, off);
    if ((tid & 63) == 0) s_part[tid >> 6] = tot;
    __syncthreads();
    const float total = s_part[0] + s_part[1] + s_part[2] + s_part[3];

    if (active) {
        float4 mean;
        mean.x = S.x / fmaxf(C.x, 1.f);
        mean.y = S.y / fmaxf(C.y, 1.f);
        mean.z = S.z / fmaxf(C.z, 1.f);
        mean.w = S.w / fmaxf(C.w, 1.f);
        if (total == 0.f) mean = ((const float4*)wv)[tid];   // wv[0,0,:]

        const float lm = len_mask[sgid];
        mean.x *= lm; mean.y *= lm; mean.z *= lm; mean.w *= lm;

        float4* out4 = (float4*)out;
        out4[(size_t)(b * 2 * NN + NN + n) * D4 + tid] = mean;

        const int   rid = rep_ids[sgid];
        const float rm  = rep_mask[sgid];
        float4 rv = ((const float4*)wv)[(size_t)(b * SS + rid) * D4 + tid];
        rv.x *= rm; rv.y *= rm; rv.z *= rm; rv.w *= rm;
        out4[(size_t)(b * 2 * NN + n) * D4 + tid] = rv;

        if (tid == 0) {
            float* masks = out + (size_t)BB * 2 * NN * DD;
            masks[b * 2 * NN + n]      = rm;
            masks[b * 2 * NN + NN + n] = lm;
        }
    }
}

extern "C" void kernel_launch(void* const* d_in, const int* in_sizes, int n_in,
                              void* d_out, int out_size, void* d_ws, size_t ws_size,
                              hipStream_t stream) {
    const float* wv       = (const float*)d_in[0];
    const int*   rep_ids  = (const int*)d_in[1];
    const float* rep_mask = (const float*)d_in[2];
    const int*   lens     = (const int*)d_in[3];
    const float* len_mask = (const float*)d_in[4];
    float*       out      = (float*)d_out;
    float*       ws_sum   = (float*)d_ws;
    float*       ws_cnt   = ws_sum + WS_N;

    zero_ws<<<(2 * WS_N / 4) / 256, 256, 0, stream>>>((float4*)d_ws);
    partial_kernel<<<BB * NTILES, 256, 0, stream>>>(wv, lens, ws_sum, ws_cnt);
    finalize_kernel<<<BB * NN, 256, 0, stream>>>(wv, rep_ids, rep_mask, len_mask,
                                                 ws_sum, ws_cnt, out);
}